// Round 7
// baseline (120.981 us; speedup 1.0000x reference)
//
#include <hip/hip_runtime.h>
#include <math.h>

#define Bq 512
#define Nq 128
#define Mq 256
#define Eq 64
#define NBANDS 32
#define LOG2E 1.4426950408889634f

// ws layout (float offsets); ~17 MB used.
#define WS_ZC 0                     // [512][128]
#define WS_P  65536                 // [512][2][32][128]: per-col A0 then A1, band-major
#define WS_MZ (65536 + 4194304)     // [512][32][2]

#define DPPADD(X, CTRL) \
    (X) += __int_as_float(__builtin_amdgcn_update_dpp(0, __float_as_int(X), (CTRL), 0xf, 0xf, true));
#define DPPMAX(X, CTRL) \
    (X) = fmaxf((X), __int_as_float(__builtin_amdgcn_update_dpp(0, __float_as_int(X), (CTRL), 0xf, 0xf, true)));

// sum over each 16-lane group (4 DPP steps, stays in-group)
__device__ __forceinline__ float red16(float x) {
    DPPADD(x, 0x0B1) DPPADD(x, 0x04E) DPPADD(x, 0x141) DPPADD(x, 0x140)
    return x;
}
// sum / max over 32 lanes (lanes 0..31)
__device__ __forceinline__ float red32sum(float x) {
    DPPADD(x, 0x0B1) DPPADD(x, 0x04E) DPPADD(x, 0x141) DPPADD(x, 0x140)
    x += __int_as_float(__builtin_amdgcn_ds_swizzle(__float_as_int(x), 0x401F));
    return x;
}
__device__ __forceinline__ float red32max(float x) {
    DPPMAX(x, 0x0B1) DPPMAX(x, 0x04E) DPPMAX(x, 0x141) DPPMAX(x, 0x140)
    x = fmaxf(x, __int_as_float(__builtin_amdgcn_ds_swizzle(__float_as_int(x), 0x401F)));
    return x;
}

// ---- kernel0: zc[col][o] = D[o,:]·z[:,col] + sigma[o]*noise[o,col] ----
extern "C" __global__ void __launch_bounds__(512)
zc_kernel(const float* __restrict__ z, const float* __restrict__ noise,
          const float* __restrict__ D, const float* __restrict__ sigma,
          float* __restrict__ ws)
{
    const int b4 = blockIdx.x * 4;
    const int t  = threadIdx.x;
    __shared__ float zs[4][256];
    for (int i = t; i < 1024; i += 512)
        zs[i >> 8][i & 255] = z[(i & 255) * Bq + b4 + (i >> 8)];
    __syncthreads();
    const int c = t >> 7, o = t & 127;
    const float4* Dr = (const float4*)(D + o * Mq);
    const float* zc = zs[c];
    float a0 = 0.f, a1 = 0.f, a2 = 0.f, a3 = 0.f;
    #pragma unroll 8
    for (int i = 0; i < 64; ++i) {
        float4 dv = Dr[i];
        a0 = fmaf(dv.x, zc[4 * i + 0], a0);
        a1 = fmaf(dv.y, zc[4 * i + 1], a1);
        a2 = fmaf(dv.z, zc[4 * i + 2], a2);
        a3 = fmaf(dv.w, zc[4 * i + 3], a3);
    }
    ws[WS_ZC + (b4 + c) * Nq + o] =
        (a0 + a1) + (a2 + a3) + sigma[o] * noise[o * Bq + b4 + c];
}

// One row S from ring slot K; optional refill with row S+8 (always in-range).
// a1 uses the PREVIOUS row's weight (wprev) with the current row's data ->
// no neighbor-row register needed.
#define ROWB(K, S, RF)                                                   \
    {                                                                    \
        float4 e0 = rA[(K)], e1 = rB[(K)];                               \
        if (RF) { const float4* rp = p4 + (size_t)((S) + 8) * 16384;     \
                  rA[(K)] = rp[0]; rB[(K)] = rp[16]; }                   \
        float d = ((fabsf(e0.x-zc0.x)+fabsf(e0.y-zc0.y)) +               \
                   (fabsf(e0.z-zc0.z)+fabsf(e0.w-zc0.w))) +              \
                  ((fabsf(e1.x-zc1.x)+fabsf(e1.y-zc1.y)) +               \
                   (fabsf(e1.z-zc1.z)+fabsf(e1.w-zc1.w)));               \
        d = red16(d);                                                    \
        float v = d * negt;                                              \
        float mnew = fmaxf(mrun, v);                                     \
        float sc = exp2f(mrun - mnew);                                   \
        float w  = exp2f(v - mnew);                                      \
        float wp = wprev * sc;                                           \
        mrun = mnew;                                                     \
        Zrun = fmaf(Zrun, sc, w);                                        \
        a00.x=fmaf(a00.x,sc,w*e0.x);  a00.y=fmaf(a00.y,sc,w*e0.y);       \
        a00.z=fmaf(a00.z,sc,w*e0.z);  a00.w=fmaf(a00.w,sc,w*e0.w);       \
        a01.x=fmaf(a01.x,sc,w*e1.x);  a01.y=fmaf(a01.y,sc,w*e1.y);       \
        a01.z=fmaf(a01.z,sc,w*e1.z);  a01.w=fmaf(a01.w,sc,w*e1.w);       \
        a10.x=fmaf(a10.x,sc,wp*e0.x); a10.y=fmaf(a10.y,sc,wp*e0.y);      \
        a10.z=fmaf(a10.z,sc,wp*e0.z); a10.w=fmaf(a10.w,sc,wp*e0.w);      \
        a11.x=fmaf(a11.x,sc,wp*e1.x); a11.y=fmaf(a11.y,sc,wp*e1.y);      \
        a11.z=fmaf(a11.z,sc,wp*e1.z); a11.w=fmaf(a11.w,sc,wp*e1.w);      \
        wprev = w;                                                       \
    }

// ---- kernel1: 512 blocks = 16 col-groups (fast) x 32 bands; 2 blocks/CU.
// Block reads 16KB CONTIGUOUS per context row (32 adjacent cols).
// Wave = 4 cols x 16 lanes x 32B. 8-deep double-register ring, no LDS.
extern "C" __global__ void __launch_bounds__(512, 4)
stream_kernel(const float* __restrict__ context,
              const float* __restrict__ temp1,
              float* __restrict__ ws)
{
    const int tid  = threadIdx.x;
    const int wave = tid >> 6;
    const int lane = tid & 63;
    const int j    = lane & 15;
    const int cg   = blockIdx.x & 15;
    const int band = blockIdx.x >> 4;
    const int col  = cg * 32 + wave * 4 + (lane >> 4);

    const int L = band * 32;
    const int H = min(1023, L + 32);   // body rows [L,H), tail row H

    const float4* p4 = (const float4*)context + (size_t)col * 32 + j;

    float4 rA[8], rB[8];
    #pragma unroll
    for (int k = 0; k < 8; ++k) {
        const float4* rp = p4 + (size_t)(L + k) * 16384;
        rA[k] = rp[0]; rB[k] = rp[16];
    }
    const float4* xp = p4 + (size_t)H * 16384;
    float4 xA = xp[0], xB = xp[16];

    const float4 zc0 = *(const float4*)(ws + WS_ZC + (size_t)col * Nq + j * 4);
    const float4 zc1 = *(const float4*)(ws + WS_ZC + (size_t)col * Nq + 64 + j * 4);
    const float negt = -LOG2E / fabsf(temp1[0]);

    float mrun = -INFINITY, Zrun = 0.f, wprev = 0.f;
    float4 a00 = make_float4(0,0,0,0), a01 = make_float4(0,0,0,0);
    float4 a10 = make_float4(0,0,0,0), a11 = make_float4(0,0,0,0);

    // 3 refilling batches + 1 final batch. All refill rows <= L+31 <= 1023.
    ROWB(0,L+ 0,1) ROWB(1,L+ 1,1) ROWB(2,L+ 2,1) ROWB(3,L+ 3,1)
    ROWB(4,L+ 4,1) ROWB(5,L+ 5,1) ROWB(6,L+ 6,1) ROWB(7,L+ 7,1)
    ROWB(0,L+ 8,1) ROWB(1,L+ 9,1) ROWB(2,L+10,1) ROWB(3,L+11,1)
    ROWB(4,L+12,1) ROWB(5,L+13,1) ROWB(6,L+14,1) ROWB(7,L+15,1)
    ROWB(0,L+16,1) ROWB(1,L+17,1) ROWB(2,L+18,1) ROWB(3,L+19,1)
    ROWB(4,L+20,1) ROWB(5,L+21,1) ROWB(6,L+22,1) ROWB(7,L+23,1)
    ROWB(0,L+24,0) ROWB(1,L+25,0) ROWB(2,L+26,0) ROWB(3,L+27,0)
    ROWB(4,L+28,0) ROWB(5,L+29,0) ROWB(6,L+30,0)
    if (L + 31 < H) ROWB(7,L+31,0)     // skipped only by band 31 (H=1023)

    // tail: a1 += w[H-1] * ctx[H]
    a10.x = fmaf(wprev, xA.x, a10.x); a10.y = fmaf(wprev, xA.y, a10.y);
    a10.z = fmaf(wprev, xA.z, a10.z); a10.w = fmaf(wprev, xA.w, a10.w);
    a11.x = fmaf(wprev, xB.x, a11.x); a11.y = fmaf(wprev, xB.y, a11.y);
    a11.z = fmaf(wprev, xB.z, a11.z); a11.w = fmaf(wprev, xB.w, a11.w);

    // per-col, band-major partial store (contiguous 32KB per col for the merge)
    float* pc = ws + WS_P + (size_t)col * (2 * NBANDS * Nq) + (size_t)band * Nq;
    *(float4*)(pc + j * 4)                     = a00;
    *(float4*)(pc + 64 + j * 4)                = a01;
    *(float4*)(pc + NBANDS * Nq + j * 4)       = a10;
    *(float4*)(pc + NBANDS * Nq + 64 + j * 4)  = a11;
    if (j == 0) {
        ws[WS_MZ + ((size_t)col * NBANDS + band) * 2]     = mrun;
        ws[WS_MZ + ((size_t)col * NBANDS + band) * 2 + 1] = Zrun;
    }
}

// ---- kernel2: merge 32 band-partials + conv contraction + MLP + softmax.
// 128 blocks x 512 threads; 4 cols per block.
extern "C" __global__ void __launch_bounds__(512)
merge_kernel(const float* __restrict__ ws,
             const float* __restrict__ z,
             const float* __restrict__ conv_w,
             const float* __restrict__ conv_b,
             const float* __restrict__ W1,
             const float* __restrict__ b1,
             const float* __restrict__ W2,
             const float* __restrict__ b2,
             const float* __restrict__ temp2,
             float* __restrict__ out)
{
    const int t   = threadIdx.x;
    const int cs  = t >> 7;            // col-sub 0..3
    const int o   = t & 127;
    const int col = blockIdx.x * 4 + cs;

    __shared__ float sscl[4][NBANDS];
    __shared__ float sGz[4];
    __shared__ __align__(16) float gA0[4][128];
    __shared__ __align__(16) float gA1[4][128];
    __shared__ __align__(16) float semb[4][128];
    __shared__ __align__(16) float szcol[4][256];
    __shared__ __align__(16) float shb[4][64];

    szcol[cs][o]       = z[o * Bq + col];
    szcol[cs][o + 128] = z[(o + 128) * Bq + col];

    // merge factors: lanes 0..31 of each col-group's first wave
    if (o < NBANDS) {
        float m  = ws[WS_MZ + ((size_t)col * NBANDS + o) * 2];
        float Zp = ws[WS_MZ + ((size_t)col * NBANDS + o) * 2 + 1];
        float gm = red32max(m);
        float sc = exp2f(m - gm);
        float gz = red32sum(sc * Zp);
        sscl[cs][o] = sc;
        if (o == 0) sGz[cs] = gz;
    }
    __syncthreads();

    {
        const float* pc = ws + WS_P + (size_t)col * (2 * NBANDS * Nq);
        float acc0 = 0.f, acc1 = 0.f;
        #pragma unroll 8
        for (int p = 0; p < NBANDS; ++p) {
            float sc = sscl[cs][p];
            acc0 = fmaf(sc, pc[(size_t)p * Nq + o], acc0);
            acc1 = fmaf(sc, pc[NBANDS * Nq + (size_t)p * Nq + o], acc1);
        }
        gA0[cs][o] = acc0;
        gA1[cs][o] = acc1;
    }
    __syncthreads();

    // embedding[o] = (w0[o,:]·A0 + w1[o,:]·A1)/Z + conv_b[o]
    {
        const float4* wr = (const float4*)(conv_w + o * 256);
        float acc = 0.f;
        #pragma unroll 8
        for (int i = 0; i < 64; ++i) {
            float4 w4 = wr[i];   // w0[o,2i], w1[o,2i], w0[o,2i+1], w1[o,2i+1]
            acc = fmaf(w4.x, gA0[cs][2 * i], acc);
            acc = fmaf(w4.y, gA1[cs][2 * i], acc);
            acc = fmaf(w4.z, gA0[cs][2 * i + 1], acc);
            acc = fmaf(w4.w, gA1[cs][2 * i + 1], acc);
        }
        semb[cs][o] = acc / sGz[cs] + conv_b[o];
    }
    __syncthreads();

    if (o < 64) {
        const float4* w1r = (const float4*)(W1 + o * (Nq + Mq));
        float acc = b1[o];
        #pragma unroll 8
        for (int i = 0; i < 32; ++i) {
            float4 wv = w1r[i];
            acc = fmaf(wv.x, semb[cs][4 * i + 0], acc);
            acc = fmaf(wv.y, semb[cs][4 * i + 1], acc);
            acc = fmaf(wv.z, semb[cs][4 * i + 2], acc);
            acc = fmaf(wv.w, semb[cs][4 * i + 3], acc);
        }
        #pragma unroll 8
        for (int i = 0; i < 64; ++i) {
            float4 wv = w1r[32 + i];
            acc = fmaf(wv.x, szcol[cs][4 * i + 0], acc);
            acc = fmaf(wv.y, szcol[cs][4 * i + 1], acc);
            acc = fmaf(wv.z, szcol[cs][4 * i + 2], acc);
            acc = fmaf(wv.w, szcol[cs][4 * i + 3], acc);
        }
        shb[cs][o] = fmaxf(acc, 0.f);
    }
    __syncthreads();

    if (o < 64) {
        const float* w2r = W2 + o * Eq;
        float acc = b2[o];
        #pragma unroll 8
        for (int jj = 0; jj < 64; ++jj) acc = fmaf(w2r[jj], shb[cs][jj], acc);
        float v = -acc * (LOG2E / fabsf(temp2[0]));
        float mx = v;
        #pragma unroll
        for (int off = 32; off > 0; off >>= 1) mx = fmaxf(mx, __shfl_xor(mx, off, 64));
        float w = exp2f(v - mx);
        float s = w;
        #pragma unroll
        for (int off = 32; off > 0; off >>= 1) s += __shfl_xor(s, off, 64);
        out[o * Bq + col] = w / s;
    }
}

extern "C" void kernel_launch(void* const* d_in, const int* in_sizes, int n_in,
                              void* d_out, int out_size, void* d_ws, size_t ws_size,
                              hipStream_t stream) {
    const float* context = (const float*)d_in[0];
    const float* z       = (const float*)d_in[1];
    const float* noise   = (const float*)d_in[2];
    const float* conv_w  = (const float*)d_in[3];
    const float* conv_b  = (const float*)d_in[4];
    const float* D       = (const float*)d_in[5];
    const float* sigma   = (const float*)d_in[6];
    const float* temp1   = (const float*)d_in[7];
    const float* W1      = (const float*)d_in[8];
    const float* b1      = (const float*)d_in[9];
    const float* W2      = (const float*)d_in[10];
    const float* b2      = (const float*)d_in[11];
    const float* temp2   = (const float*)d_in[12];
    float* out = (float*)d_out;
    float* ws  = (float*)d_ws;

    zc_kernel<<<dim3(128), dim3(512), 0, stream>>>(z, noise, D, sigma, ws);
    stream_kernel<<<dim3(512), dim3(512), 0, stream>>>(context, temp1, ws);
    merge_kernel<<<dim3(128), dim3(512), 0, stream>>>(ws, z, conv_w, conv_b,
                                                      W1, b1, W2, b2, temp2, out);
}

// Round 8
// 97.055 us; speedup vs baseline: 1.2465x; 1.2465x over previous
//
#include <hip/hip_runtime.h>
#include <math.h>

#define Bq 512
#define Nq 128
#define Mq 256
#define Eq 64
#define LOG2E 1.4426950408889634f

// ws: per (col,half) partial = {A0[128], A1[128], m, Z, pad...} = 264 floats.
#define PSTRIDE 264

// Wave64 sum-reduce via DPP; uniform result on all lanes via readlane(63).
__device__ __forceinline__ float waveReduceSumAll(float x) {
    x += __int_as_float(__builtin_amdgcn_update_dpp(0, __float_as_int(x), 0x111, 0xf, 0xf, true)); // row_shr:1
    x += __int_as_float(__builtin_amdgcn_update_dpp(0, __float_as_int(x), 0x112, 0xf, 0xf, true)); // row_shr:2
    x += __int_as_float(__builtin_amdgcn_update_dpp(0, __float_as_int(x), 0x114, 0xf, 0xf, true)); // row_shr:4
    x += __int_as_float(__builtin_amdgcn_update_dpp(0, __float_as_int(x), 0x118, 0xf, 0xf, true)); // row_shr:8
    x += __int_as_float(__builtin_amdgcn_update_dpp(0, __float_as_int(x), 0x142, 0xf, 0xf, true)); // row_bcast:15
    x += __int_as_float(__builtin_amdgcn_update_dpp(0, __float_as_int(x), 0x143, 0xf, 0xf, true)); // row_bcast:31
    return __int_as_float(__builtin_amdgcn_readlane(__float_as_int(x), 63));
}

// One distance row S from ring slot K; optional refill with row S+8.
// a1 uses previous row's weight (wprev) with current row's data.
#define ROWB(K, S, RF)                                                   \
    {                                                                    \
        float2 e = buf[(K)];                                             \
        if (RF) buf[(K)] = p2[(size_t)((S) + 8) * 32768];                \
        float d = fabsf(e.x - zcx) + fabsf(e.y - zcy);                   \
        d = waveReduceSumAll(d);                                         \
        float v = d * negt;                                              \
        float mnew = fmaxf(mrun, v);                                     \
        float sc = exp2f(mrun - mnew);                                   \
        float w  = exp2f(v - mnew);                                      \
        float wp = wprev * sc;                                           \
        mrun = mnew;                                                     \
        Zrun = fmaf(Zrun, sc, w);                                        \
        a0x = fmaf(a0x, sc, w * e.x);                                    \
        a0y = fmaf(a0y, sc, w * e.y);                                    \
        a1x = fmaf(a1x, sc, wp * e.x);                                   \
        a1y = fmaf(a1y, sc, wp * e.y);                                   \
        wprev = w;                                                       \
    }

// ---- kernel1: 1024 blocks = 512 cols x 2 row-halves; 4 blocks/CU, 32 waves/CU.
// Block: 1 column, 8 waves x 64 rows, float2/lane, 8-deep register ring (~45 VGPR).
extern "C" __global__ void __launch_bounds__(512, 8)
stream_kernel(const float* __restrict__ context,
              const float* __restrict__ z,
              const float* __restrict__ noise,
              const float* __restrict__ D,
              const float* __restrict__ sigma,
              const float* __restrict__ temp1,
              float* __restrict__ ws)
{
    const int tid  = threadIdx.x;
    const int wave = tid >> 6;
    const int lane = tid & 63;
    const int col  = blockIdx.x >> 1;
    const int half = blockIdx.x & 1;

    __shared__ __align__(16) float sA0[8][128];
    __shared__ __align__(16) float sA1[8][128];
    __shared__ float smx[8];
    __shared__ float sZ[8];
    __shared__ __align__(16) float szc[128];
    __shared__ __align__(16) float szcol[256];

    const int lo = half * 512 + wave * 64;
    const int hi = min(1023, lo + 64);           // rows [lo,hi); hi row = a1-tail neighbor

    const float2* p2 = (const float2*)context + (size_t)col * 64 + lane; // row stride 32768

    // ring preload first: 8 row loads + tail neighbor fly under phase 0
    float2 buf[8];
    #pragma unroll
    for (int j = 0; j < 8; ++j)
        buf[j] = p2[(size_t)(lo + j) * 32768];
    float2 xtra = p2[(size_t)hi * 32768];

    // phase 0: z column + zc = D@z + sigma*noise
    if (tid < 256) szcol[tid] = z[tid * Bq + col];
    __syncthreads();
    if (tid < 128) {
        const float4* Drow = (const float4*)(D + tid * Mq);
        float c0 = 0.f, c1 = 0.f, c2 = 0.f, c3 = 0.f;
        #pragma unroll 8
        for (int i = 0; i < 64; ++i) {
            float4 dv = Drow[i];
            c0 = fmaf(dv.x, szcol[4 * i + 0], c0);
            c1 = fmaf(dv.y, szcol[4 * i + 1], c1);
            c2 = fmaf(dv.z, szcol[4 * i + 2], c2);
            c3 = fmaf(dv.w, szcol[4 * i + 3], c3);
        }
        szc[tid] = (c0 + c1) + (c2 + c3) + sigma[tid] * noise[tid * Bq + col];
    }
    __syncthreads();

    const float zcx = szc[2 * lane];
    const float zcy = szc[2 * lane + 1];
    const float negt = -LOG2E / fabsf(temp1[0]);

    float mrun = -INFINITY, Zrun = 0.f, wprev = 0.f;
    float a0x = 0.f, a0y = 0.f, a1x = 0.f, a1y = 0.f;

    // body: refilling batches while rb+8 < hi (refill rows <= hi+... <= 1023 always)
    int rb = lo;
    for (; rb + 8 < hi; rb += 8) {
        ROWB(0, rb+0, 1) ROWB(1, rb+1, 1) ROWB(2, rb+2, 1) ROWB(3, rb+3, 1)
        ROWB(4, rb+4, 1) ROWB(5, rb+5, 1) ROWB(6, rb+6, 1) ROWB(7, rb+7, 1)
    }
    // tail: remaining rows rb..hi-1 (7 or 8), resident in slots 0..7
    #pragma unroll
    for (int j = 0; j < 8; ++j) {
        if (rb + j < hi)
            ROWB(j, rb + j, 0)
    }
    // a1 tail: += w[hi-1] * ctx[hi]
    a1x = fmaf(wprev, xtra.x, a1x);
    a1y = fmaf(wprev, xtra.y, a1y);

    // in-block merge of 8 wave states
    *(float2*)&sA0[wave][2 * lane] = make_float2(a0x, a0y);
    *(float2*)&sA1[wave][2 * lane] = make_float2(a1x, a1y);
    if (lane == 0) { smx[wave] = mrun; sZ[wave] = Zrun; }
    __syncthreads();

    float gm = smx[0];
    #pragma unroll
    for (int k = 1; k < 8; ++k) gm = fmaxf(gm, smx[k]);
    float scl[8];
    float Gz = 0.f;
    #pragma unroll
    for (int k = 0; k < 8; ++k) { scl[k] = exp2f(smx[k] - gm); Gz = fmaf(scl[k], sZ[k], Gz); }

    float* pb = ws + (size_t)(col * 2 + half) * PSTRIDE;
    if (tid < 128) {
        float acc = 0.f;
        #pragma unroll
        for (int k = 0; k < 8; ++k) acc = fmaf(scl[k], sA0[k][tid], acc);
        pb[tid] = acc;
    } else if (tid < 256) {
        const int t = tid - 128;
        float acc = 0.f;
        #pragma unroll
        for (int k = 0; k < 8; ++k) acc = fmaf(scl[k], sA1[k][t], acc);
        pb[128 + t] = acc;
    } else if (tid == 256) {
        pb[256] = gm;
        pb[257] = Gz;
    }
}

// ---- kernel2: combine 2 half-partials + conv contraction + MLP + softmax.
// 128 blocks x 512 threads; 4 cols per block.
extern "C" __global__ void __launch_bounds__(512)
epilogue_kernel(const float* __restrict__ ws,
                const float* __restrict__ z,
                const float* __restrict__ conv_w,
                const float* __restrict__ conv_b,
                const float* __restrict__ W1,
                const float* __restrict__ b1,
                const float* __restrict__ W2,
                const float* __restrict__ b2,
                const float* __restrict__ temp2,
                float* __restrict__ out)
{
    const int t   = threadIdx.x;
    const int cs  = t >> 7;            // col-sub 0..3
    const int o   = t & 127;
    const int col = blockIdx.x * 4 + cs;

    __shared__ __align__(16) float gA0[4][128];
    __shared__ __align__(16) float gA1[4][128];
    __shared__ __align__(16) float semb[4][128];
    __shared__ __align__(16) float szcol[4][256];
    __shared__ __align__(16) float shb[4][64];

    szcol[cs][o]       = z[o * Bq + col];
    szcol[cs][o + 128] = z[(o + 128) * Bq + col];

    const float* P0 = ws + (size_t)(col * 2 + 0) * PSTRIDE;
    const float* P1 = ws + (size_t)(col * 2 + 1) * PSTRIDE;
    const float m0 = P0[256], Z0 = P0[257];
    const float m1 = P1[256], Z1 = P1[257];
    const float gm = fmaxf(m0, m1);
    const float s0 = exp2f(m0 - gm), s1 = exp2f(m1 - gm);
    const float Gz = fmaf(s0, Z0, s1 * Z1);    // fixed order -> deterministic

    gA0[cs][o] = fmaf(s0, P0[o],       s1 * P1[o]);
    gA1[cs][o] = fmaf(s0, P0[128 + o], s1 * P1[128 + o]);
    __syncthreads();

    // embedding[o] = (w0[o,:]·A0 + w1[o,:]·A1)/Z + conv_b[o]
    {
        const float4* wr = (const float4*)(conv_w + o * 256);
        float acc = 0.f;
        #pragma unroll 8
        for (int i = 0; i < 64; ++i) {
            float4 w4 = wr[i];   // w0[o,2i], w1[o,2i], w0[o,2i+1], w1[o,2i+1]
            acc = fmaf(w4.x, gA0[cs][2 * i], acc);
            acc = fmaf(w4.y, gA1[cs][2 * i], acc);
            acc = fmaf(w4.z, gA0[cs][2 * i + 1], acc);
            acc = fmaf(w4.w, gA1[cs][2 * i + 1], acc);
        }
        semb[cs][o] = acc / Gz + conv_b[o];
    }
    __syncthreads();

    if (o < 64) {
        const float4* w1r = (const float4*)(W1 + o * (Nq + Mq));
        float acc = b1[o];
        #pragma unroll 8
        for (int i = 0; i < 32; ++i) {
            float4 wv = w1r[i];
            acc = fmaf(wv.x, semb[cs][4 * i + 0], acc);
            acc = fmaf(wv.y, semb[cs][4 * i + 1], acc);
            acc = fmaf(wv.z, semb[cs][4 * i + 2], acc);
            acc = fmaf(wv.w, semb[cs][4 * i + 3], acc);
        }
        #pragma unroll 8
        for (int i = 0; i < 64; ++i) {
            float4 wv = w1r[32 + i];
            acc = fmaf(wv.x, szcol[cs][4 * i + 0], acc);
            acc = fmaf(wv.y, szcol[cs][4 * i + 1], acc);
            acc = fmaf(wv.z, szcol[cs][4 * i + 2], acc);
            acc = fmaf(wv.w, szcol[cs][4 * i + 3], acc);
        }
        shb[cs][o] = fmaxf(acc, 0.f);
    }
    __syncthreads();

    if (o < 64) {
        const float* w2r = W2 + o * Eq;
        float acc = b2[o];
        #pragma unroll 8
        for (int jj = 0; jj < 64; ++jj) acc = fmaf(w2r[jj], shb[cs][jj], acc);
        float v = -acc * (LOG2E / fabsf(temp2[0]));
        float mx = v;
        #pragma unroll
        for (int off = 32; off > 0; off >>= 1) mx = fmaxf(mx, __shfl_xor(mx, off, 64));
        float w = exp2f(v - mx);
        float s = w;
        #pragma unroll
        for (int off = 32; off > 0; off >>= 1) s += __shfl_xor(s, off, 64);
        out[o * Bq + col] = w / s;
    }
}

extern "C" void kernel_launch(void* const* d_in, const int* in_sizes, int n_in,
                              void* d_out, int out_size, void* d_ws, size_t ws_size,
                              hipStream_t stream) {
    const float* context = (const float*)d_in[0];
    const float* z       = (const float*)d_in[1];
    const float* noise   = (const float*)d_in[2];
    const float* conv_w  = (const float*)d_in[3];
    const float* conv_b  = (const float*)d_in[4];
    const float* D       = (const float*)d_in[5];
    const float* sigma   = (const float*)d_in[6];
    const float* temp1   = (const float*)d_in[7];
    const float* W1      = (const float*)d_in[8];
    const float* b1      = (const float*)d_in[9];
    const float* W2      = (const float*)d_in[10];
    const float* b2      = (const float*)d_in[11];
    const float* temp2   = (const float*)d_in[12];
    float* out = (float*)d_out;
    float* ws  = (float*)d_ws;

    stream_kernel<<<dim3(1024), dim3(512), 0, stream>>>(
        context, z, noise, D, sigma, temp1, ws);
    epilogue_kernel<<<dim3(128), dim3(512), 0, stream>>>(
        ws, z, conv_w, conv_b, W1, b1, W2, b2, temp2, out);
}

// Round 9
// 67.319 us; speedup vs baseline: 1.7971x; 1.4417x over previous
//
#include <hip/hip_runtime.h>
#include <math.h>

#define Bq 512
#define Nq 128
#define Mq 256
#define Eq 64
#define LOG2E 1.4426950408889634f

#define DPPADD(X, CTRL) \
    (X) += __int_as_float(__builtin_amdgcn_update_dpp(0, __float_as_int(X), (CTRL), 0xf, 0xf, true));

// Sum across each 32-lane half; result uniform within the half.
__device__ __forceinline__ float halfReduce32(float x) {
    DPPADD(x, 0x0B1)  // quad_perm xor1
    DPPADD(x, 0x04E)  // quad_perm xor2
    DPPADD(x, 0x141)  // row_half_mirror (xor4)
    DPPADD(x, 0x140)  // row_mirror (xor8)
    x += __int_as_float(__builtin_amdgcn_ds_swizzle(__float_as_int(x), 0x401F)); // xor16
    return x;
}

// One distance row S (absolute) from ring slot K; optional refill with row S+8.
// Each 32-lane half holds the FULL 128-float row as float4/lane; all softmax
// scalars are uniform-per-half. a1 uses previous row's weight (wprev).
#define ROWB(K, S, RF)                                                    \
    {                                                                     \
        float4 e = buf[(K)];                                              \
        if (RF) buf[(K)] = pr[(size_t)((S) + 8) * 16384];                 \
        float d = (fabsf(e.x - zc0.x) + fabsf(e.y - zc0.y)) +             \
                  (fabsf(e.z - zc0.z) + fabsf(e.w - zc0.w));              \
        d = halfReduce32(d);                                              \
        float v = d * negt;                                               \
        float mnew = fmaxf(mrun, v);                                      \
        float sc = exp2f(mrun - mnew);                                    \
        float w  = exp2f(v - mnew);                                       \
        float wp = wprev * sc;                                            \
        mrun = mnew;                                                      \
        Zrun = fmaf(Zrun, sc, w);                                         \
        a0.x = fmaf(a0.x, sc, w * e.x);   a0.y = fmaf(a0.y, sc, w * e.y); \
        a0.z = fmaf(a0.z, sc, w * e.z);   a0.w = fmaf(a0.w, sc, w * e.w); \
        a1.x = fmaf(a1.x, sc, wp * e.x);  a1.y = fmaf(a1.y, sc, wp * e.y);\
        a1.z = fmaf(a1.z, sc, wp * e.z);  a1.w = fmaf(a1.w, sc, wp * e.w);\
        wprev = w;                                                        \
    }

extern "C" __global__ void __launch_bounds__(512, 4)
gating_kernel(const float* __restrict__ context,
              const float* __restrict__ z,
              const float* __restrict__ noise,
              const float* __restrict__ conv_w,
              const float* __restrict__ conv_b,
              const float* __restrict__ D,
              const float* __restrict__ sigma,
              const float* __restrict__ temp1,
              const float* __restrict__ W1,
              const float* __restrict__ b1,
              const float* __restrict__ W2,
              const float* __restrict__ b2,
              const float* __restrict__ temp2,
              float* __restrict__ out)
{
    const int b    = blockIdx.x;
    const int tid  = threadIdx.x;
    const int wave = tid >> 6;
    const int lane = tid & 63;
    const int half = lane >> 5;
    const int l5   = lane & 31;
    const int idx  = wave * 2 + half;          // 16 half-wave states

    __shared__ __align__(16) float sA0[16][128];
    __shared__ __align__(16) float sA1[16][128];
    __shared__ float smx[16];
    __shared__ float sZ[16];
    __shared__ __align__(16) float gA0[128];
    __shared__ __align__(16) float gA1[128];
    __shared__ __align__(16) float semb[128];
    __shared__ __align__(16) float szc[128];
    __shared__ __align__(16) float szcol[256];
    __shared__ __align__(16) float shb[64];

    // half-wave's own 64-row band
    const int myLo = wave * 128 + half * 64;
    const int myHi = min(1023, myLo + 64);     // rows [myLo,myHi); row myHi = a1 tail

    // lane's 16B slice of the 512B row; row stride 16384 float4s
    const float4* pr = (const float4*)context + (size_t)b * 32 + l5;

    // ring preload BEFORE phase 0 (loads fly under the D@z prologue)
    float4 buf[8];
    #pragma unroll
    for (int j = 0; j < 8; ++j)
        buf[j] = pr[(size_t)(myLo + j) * 16384];
    float4 xtra = pr[(size_t)myHi * 16384];

    // ---- phase 0: stage z column; zc = D @ z + sigma * noise ----
    if (tid < 256) szcol[tid] = z[tid * Bq + b];
    __syncthreads();
    if (tid < 128) {
        const float4* Drow = (const float4*)(D + tid * Mq);
        float c0 = 0.f, c1 = 0.f, c2 = 0.f, c3 = 0.f;
        #pragma unroll 8
        for (int i = 0; i < 64; ++i) {
            float4 dv = Drow[i];
            c0 = fmaf(dv.x, szcol[4 * i + 0], c0);
            c1 = fmaf(dv.y, szcol[4 * i + 1], c1);
            c2 = fmaf(dv.z, szcol[4 * i + 2], c2);
            c3 = fmaf(dv.w, szcol[4 * i + 3], c3);
        }
        szc[tid] = (c0 + c1) + (c2 + c3) + sigma[tid] * noise[tid * Bq + b];
    }
    __syncthreads();

    const float4 zc0 = *(const float4*)&szc[l5 * 4];
    const float negt = -LOG2E / fabsf(temp1[0]);

    float mrun = -INFINITY, Zrun = 0.f, wprev = 0.f;
    float4 a0 = make_float4(0.f, 0.f, 0.f, 0.f);
    float4 a1 = make_float4(0.f, 0.f, 0.f, 0.f);

    // body: refilling batches (refill rows provably <= 1023)
    int rb = myLo;
    for (; rb + 8 < myHi; rb += 8) {
        ROWB(0, rb+0, 1) ROWB(1, rb+1, 1) ROWB(2, rb+2, 1) ROWB(3, rb+3, 1)
        ROWB(4, rb+4, 1) ROWB(5, rb+5, 1) ROWB(6, rb+6, 1) ROWB(7, rb+7, 1)
    }
    // tail: remaining rows rb..myHi-1 resident in slots 0..7
    #pragma unroll
    for (int j = 0; j < 8; ++j) {
        if (rb + j < myHi)
            ROWB(j, rb + j, 0)
    }
    // a1 tail: += w[myHi-1] * ctx[myHi]
    a1.x = fmaf(wprev, xtra.x, a1.x); a1.y = fmaf(wprev, xtra.y, a1.y);
    a1.z = fmaf(wprev, xtra.z, a1.z); a1.w = fmaf(wprev, xtra.w, a1.w);

    // ---- merge 16 half-wave states ----
    *(float4*)&sA0[idx][l5 * 4] = a0;
    *(float4*)&sA1[idx][l5 * 4] = a1;
    if (l5 == 0) { smx[idx] = mrun; sZ[idx] = Zrun; }
    __syncthreads();

    float gm = smx[0];
    #pragma unroll
    for (int k = 1; k < 16; ++k) gm = fmaxf(gm, smx[k]);
    float scl[16];
    float Gz = 0.f;
    #pragma unroll
    for (int k = 0; k < 16; ++k) { scl[k] = exp2f(smx[k] - gm); Gz = fmaf(scl[k], sZ[k], Gz); }

    if (tid < 128) {
        float acc = 0.f;
        #pragma unroll
        for (int k = 0; k < 16; ++k) acc = fmaf(scl[k], sA0[k][tid], acc);
        gA0[tid] = acc;
    } else if (tid < 256) {
        const int t = tid - 128;
        float acc = 0.f;
        #pragma unroll
        for (int k = 0; k < 16; ++k) acc = fmaf(scl[k], sA1[k][t], acc);
        gA1[t] = acc;
    }
    __syncthreads();

    // ---- embedding[o] = (w0[o,:]·A0 + w1[o,:]·A1)/Z + conv_b[o] ----
    if (tid < 128) {
        const float4* wr = (const float4*)(conv_w + tid * 256);
        float acc = 0.f;
        #pragma unroll 8
        for (int i = 0; i < 64; ++i) {
            float4 w4 = wr[i];   // w0[o,2i], w1[o,2i], w0[o,2i+1], w1[o,2i+1]
            acc = fmaf(w4.x, gA0[2 * i], acc);
            acc = fmaf(w4.y, gA1[2 * i], acc);
            acc = fmaf(w4.z, gA0[2 * i + 1], acc);
            acc = fmaf(w4.w, gA1[2 * i + 1], acc);
        }
        semb[tid] = acc / Gz + conv_b[tid];
    }
    __syncthreads();

    // ---- MLP layer 1 ----
    if (tid < 64) {
        const float* w1r = W1 + tid * (Nq + Mq);
        float acc = b1[tid];
        #pragma unroll 8
        for (int i = 0; i < 128; ++i) acc = fmaf(w1r[i], semb[i], acc);
        #pragma unroll 8
        for (int i = 0; i < 256; ++i) acc = fmaf(w1r[128 + i], szcol[i], acc);
        shb[tid] = fmaxf(acc, 0.f);
    }
    __syncthreads();

    // ---- MLP layer 2 + softmax over E ----
    if (tid < 64) {
        const float* w2r = W2 + tid * Eq;
        float acc = b2[tid];
        #pragma unroll 8
        for (int j = 0; j < 64; ++j) acc = fmaf(w2r[j], shb[j], acc);
        float v = -acc * (LOG2E / fabsf(temp2[0]));
        float mx = v;
        #pragma unroll
        for (int off = 32; off > 0; off >>= 1) mx = fmaxf(mx, __shfl_xor(mx, off, 64));
        float w = exp2f(v - mx);
        float s = w;
        #pragma unroll
        for (int off = 32; off > 0; off >>= 1) s += __shfl_xor(s, off, 64);
        out[tid * Bq + b] = w / s;
    }
}

extern "C" void kernel_launch(void* const* d_in, const int* in_sizes, int n_in,
                              void* d_out, int out_size, void* d_ws, size_t ws_size,
                              hipStream_t stream) {
    const float* context = (const float*)d_in[0];
    const float* z       = (const float*)d_in[1];
    const float* noise   = (const float*)d_in[2];
    const float* conv_w  = (const float*)d_in[3];
    const float* conv_b  = (const float*)d_in[4];
    const float* D       = (const float*)d_in[5];
    const float* sigma   = (const float*)d_in[6];
    const float* temp1   = (const float*)d_in[7];
    const float* W1      = (const float*)d_in[8];
    const float* b1      = (const float*)d_in[9];
    const float* W2      = (const float*)d_in[10];
    const float* b2      = (const float*)d_in[11];
    const float* temp2   = (const float*)d_in[12];
    float* out = (float*)d_out;

    gating_kernel<<<dim3(Bq), dim3(512), 0, stream>>>(
        context, z, noise, conv_w, conv_b, D, sigma, temp1,
        W1, b1, W2, b2, temp2, out);
}